// Round 5
// baseline (4610.268 us; speedup 1.0000x reference)
//
#include <hip/hip_runtime.h>

#define T_TOK 1024
#define D_HID 2048
#define NEXP 32
#define I_EXP 1408
#define TOPK 6
#define NGRP 8
#define GSIZE 4
#define TOPG 3
#define SHI 2816
#define RSCALE 2.5f

typedef __attribute__((ext_vector_type(8))) short short8;
typedef __attribute__((ext_vector_type(4))) float floatx4;

#define SCHED0 __builtin_amdgcn_sched_barrier(0)
#define SBAR __builtin_amdgcn_s_barrier()
#define LGKM0 asm volatile("s_waitcnt lgkmcnt(0)" ::: "memory")
#define VMW(n) asm volatile("s_waitcnt vmcnt(" #n ")" ::: "memory")

__device__ __forceinline__ unsigned short f2b(float f) {
  unsigned int u = __float_as_uint(f);
  u += 0x7fffu + ((u >> 16) & 1u);   // RNE
  return (unsigned short)(u >> 16);
}

__device__ __forceinline__ void gld_lds16(const void* g, void* l) {
  __builtin_amdgcn_global_load_lds(
      (const __attribute__((address_space(1))) unsigned int*)g,
      (__attribute__((address_space(3))) unsigned int*)l, 16, 0, 0);
}

__device__ __forceinline__ uint4 pack8(const float* v) {
  uint4 o;
  o.x = (unsigned)f2b(v[0]) | ((unsigned)f2b(v[1]) << 16);
  o.y = (unsigned)f2b(v[2]) | ((unsigned)f2b(v[3]) << 16);
  o.z = (unsigned)f2b(v[4]) | ((unsigned)f2b(v[5]) << 16);
  o.w = (unsigned)f2b(v[6]) | ((unsigned)f2b(v[7]) << 16);
  return o;
}

__device__ __forceinline__ uint2 pack4(const float* v) {
  uint2 o;
  o.x = (unsigned)f2b(v[0]) | ((unsigned)f2b(v[1]) << 16);
  o.y = (unsigned)f2b(v[2]) | ((unsigned)f2b(v[3]) << 16);
  return o;
}

// ---------------- routing: one block (1 wave) per token ----------------
__global__ __launch_bounds__(64) void k_route(
    const float* __restrict__ x, const float* __restrict__ gw,
    const float* __restrict__ bias, int* __restrict__ tki, float* __restrict__ tkw)
{
  int t = blockIdx.x;
  __shared__ float xs[D_HID];
  __shared__ float sc[NEXP], cor[NEXP];
  int lane = threadIdx.x;
  for (int d = lane * 4; d < D_HID; d += 64 * 4)
    *(float4*)(xs + d) = *(const float4*)(x + (size_t)t * D_HID + d);
  __syncthreads();
  if (lane < NEXP) {
    float acc = 0.f;
    for (int d = 0; d < D_HID; ++d) acc += xs[d] * gw[d * NEXP + lane];
    float s = 1.f / (1.f + expf(-acc));
    sc[lane] = s;
    cor[lane] = s + bias[lane];
  }
  __syncthreads();
  if (lane == 0) {
    float gs[NGRP];
    for (int g = 0; g < NGRP; ++g) {
      float m1 = -INFINITY, m2 = -INFINITY;
      for (int j = 0; j < GSIZE; ++j) {
        float v = cor[g * GSIZE + j];
        if (v > m1) { m2 = m1; m1 = v; } else if (v > m2) m2 = v;
      }
      gs[g] = m1 + m2;
    }
    unsigned gmask = 0;
    for (int rr = 0; rr < TOPG; ++rr) {
      int bi = -1; float bv = -INFINITY;
      for (int g = 0; g < NGRP; ++g)
        if (!((gmask >> g) & 1) && gs[g] > bv) { bv = gs[g]; bi = g; }
      gmask |= 1u << bi;
    }
    unsigned used = 0;
    float wsum = 0.f;
    int idxs[TOPK]; float wsel[TOPK];
    for (int rr = 0; rr < TOPK; ++rr) {
      int bi = -1; float bv = -INFINITY;
      for (int e = 0; e < NEXP; ++e) {
        if (!((gmask >> (e / GSIZE)) & 1)) continue;
        if ((used >> e) & 1) continue;
        if (cor[e] > bv) { bv = cor[e]; bi = e; }
      }
      used |= 1u << bi;
      idxs[rr] = bi; wsel[rr] = sc[bi]; wsum += sc[bi];
    }
    float inv = 1.f / (wsum + 1e-20f);
    for (int rr = 0; rr < TOPK; ++rr) {
      tki[t * TOPK + rr] = idxs[rr];
      tkw[t * TOPK + rr] = wsel[rr] * inv;
    }
  }
}

// ---------------- counts + offsets (single block) ----------------
__global__ __launch_bounds__(256) void k_count(const int* __restrict__ tki,
                                               int* __restrict__ cnt, int* __restrict__ offp)
{
  __shared__ int c[NEXP];
  if (threadIdx.x < NEXP) c[threadIdx.x] = 0;
  __syncthreads();
  for (int i = threadIdx.x; i < T_TOK * TOPK; i += 256) atomicAdd(&c[tki[i]], 1);
  __syncthreads();
  if (threadIdx.x == 0) {
    int s = 0;
    for (int e = 0; e < NEXP; ++e) { offp[e] = s; cnt[e] = c[e]; s += c[e]; }
    offp[NEXP] = s;
  }
}

// ---------------- deterministic compaction: one wave per expert ----------------
__global__ __launch_bounds__(64) void k_compact(
    const int* __restrict__ tki, const float* __restrict__ tkw,
    const int* __restrict__ offp, int* __restrict__ tok, float* __restrict__ wts)
{
  int e = blockIdx.x, lane = threadIdx.x;
  int base = offp[e];
  for (int t0 = 0; t0 < T_TOK; t0 += 64) {
    int t = t0 + lane;
    int found = -1;
    for (int j = 0; j < TOPK; ++j)
      if (tki[t * TOPK + j] == e) found = j;
    unsigned long long m = __ballot(found >= 0);
    if (found >= 0) {
      int pos = base + __popcll(m & ((1ull << lane) - 1ull));
      tok[pos] = t;
      wts[pos] = tkw[t * TOPK + found];
    }
    base += __popcll(m);
  }
}

// ---------------- fp32 -> bf16 cast of hidden states ----------------
__global__ __launch_bounds__(256) void k_cast(const float* __restrict__ x,
                                              unsigned short* __restrict__ xb, int n4)
{
  int i = blockIdx.x * 256 + threadIdx.x;
  if (i < n4) {
    float4 v = ((const float4*)x)[i];
    ushort4 o;
    o.x = f2b(v.x); o.y = f2b(v.y); o.z = f2b(v.z); o.w = f2b(v.w);
    ((ushort4*)xb)[i] = o;
  }
}

// =================================================================
// Gate+Up fused grouped GEMM, routed (y<NEXP) + shared (y==NEXP) merged.
// 512 thr / 8 waves (4M x 2N), tile 256m x 64n, BK=32.
// A: gld_lds, granule layout [koff][m] (conflict-free b128 frag reads).
// B: per-thread k-run (8 coalesced dwords -> f2b -> 1 ds_write_b128),
//    [n][k] pad 36 (18n mod 32 all-distinct -> conflict-free).
// Pipeline: B depth-2 in regs, counted vmcnt(8) keeps loads in flight
// across raw s_barrier; A depth-1 (L2-resident source).
// =================================================================
__global__ __launch_bounds__(512, 4) void k_gateup4(
    const unsigned short* __restrict__ xb,
    const float* __restrict__ wg_r, const float* __restrict__ wu_r,
    const float* __restrict__ wsg, const float* __restrict__ wsu,
    const int* __restrict__ offp, const int* __restrict__ cnt,
    const int* __restrict__ tok,
    unsigned short* __restrict__ hb, unsigned short* __restrict__ sh)
{
  const int ey = blockIdx.y;
  const bool se = (ey == NEXP);
  const int N = se ? SHI : I_EXP;
  if (blockIdx.x * 64 >= N) return;
  const int n0 = blockIdx.x * 64;

  int rowbase, nrows;
  if (se) { rowbase = 0; nrows = T_TOK; }
  else    { rowbase = offp[ey]; nrows = cnt[ey]; }
  if (nrows <= 0) return;

  const float* wgp = se ? wsg : wg_r + (size_t)ey * D_HID * I_EXP;
  const float* wup = se ? wsu : wu_r + (size_t)ey * D_HID * I_EXP;
  unsigned short* hout = se ? sh : hb;

  __shared__ __align__(16) unsigned short As[2][8192];        // [buf][g*8], g=koff*256+m
  __shared__ __align__(16) unsigned short Bls[2][2][64 * 36]; // [buf][mat][n*36+k]

  const int tid = threadIdx.x;
  const int wid = tid >> 6, lane = tid & 63;
  const int c = lane & 15, r = lane >> 4;
  const int wr = wid >> 1, wc = wid & 1;

  // B staging mapping
  const int mat = wid >> 2;          // 0=gate, 1=up
  const int bko = wid & 3;           // k-octet
  const float* bsrc = (mat ? wup : wgp) + (size_t)(bko * 8) * N + n0 + lane;
  const int bwoff = lane * 36 + bko * 8;

  // frag offsets
  int aoff[4];
  #pragma unroll
  for (int mf = 0; mf < 4; ++mf)
    aoff[mf] = (r * 256 + wr * 64 + mf * 16 + c) * 8;
  int boff[2];
  #pragma unroll
  for (int nf = 0; nf < 2; ++nf)
    boff[nf] = (wc * 32 + nf * 16 + c) * 36 + r * 8;

  const int NK = D_HID / 32;   // 64

  for (int m0 = 0; m0 < nrows; m0 += 256) {
    const unsigned short* ga;
    {
      int rl = min(m0 + (tid & 255), nrows - 1);
      int tA = se ? (m0 + (tid & 255) < nrows ? m0 + (tid & 255) : nrows - 1)
                  : tok[rowbase + rl];
      ga = xb + (size_t)tA * D_HID + (tid >> 8) * 8;
    }

    floatx4 accg[4][2] = {};
    floatx4 accu[4][2] = {};
    float br1[8], br2[8];

    // prologue: B(0) via br2, A(0), B(1) -> br1
    #pragma unroll
    for (int j = 0; j < 8; ++j) br2[j] = bsrc[(size_t)j * N];
    gld_lds16(ga, &As[0][(size_t)tid * 8]);
    gld_lds16(ga + 16, &As[0][(size_t)(512 + tid) * 8]);
    #pragma unroll
    for (int j = 0; j < 8; ++j) br1[j] = bsrc[(size_t)(32 + j) * N];
    { uint4 pw = pack8(br2); *(uint4*)&Bls[0][mat][bwoff] = pw; }
    LGKM0; VMW(8); SBAR; SCHED0;

#define GU_STEP(BUF, KT, BRW, BRL)                                            \
    {                                                                         \
      const int kt_ = (KT);                                                   \
      const bool hA = (kt_ + 1 < NK), hB = (kt_ + 2 < NK);                    \
      if (hA) {                                                               \
        const unsigned short* gap = ga + (kt_ + 1) * 32;                      \
        gld_lds16(gap, &As[BUF ^ 1][(size_t)tid * 8]);                        \
        gld_lds16(gap + 16, &As[BUF ^ 1][(size_t)(512 + tid) * 8]);           \
      }                                                                       \
      if (hB) {                                                               \
        const float* bs_ = bsrc + (size_t)(kt_ + 2) * 32 * N;                 \
        _Pragma("unroll")                                                     \
        for (int j = 0; j < 8; ++j) BRL[j] = bs_[(size_t)j * N];              \
      }                                                                       \
      if (hA) { uint4 pw = pack8(BRW); *(uint4*)&Bls[BUF ^ 1][mat][bwoff] = pw; } \
      short8 af[4];                                                           \
      _Pragma("unroll")                                                       \
      for (int mf = 0; mf < 4; ++mf) af[mf] = *(const short8*)&As[BUF][aoff[mf]]; \
      __builtin_amdgcn_s_setprio(1);                                          \
      _Pragma("unroll")                                                       \
      for (int nf = 0; nf < 2; ++nf) {                                        \
        short8 fg = *(const short8*)&Bls[BUF][0][boff[nf]];                   \
        short8 fu = *(const short8*)&Bls[BUF][1][boff[nf]];                   \
        _Pragma("unroll")                                                     \
        for (int mf = 0; mf < 4; ++mf) {                                      \
          accg[mf][nf] = __builtin_amdgcn_mfma_f32_16x16x32_bf16(af[mf], fg, accg[mf][nf], 0, 0, 0); \
          accu[mf][nf] = __builtin_amdgcn_mfma_f32_16x16x32_bf16(af[mf], fu, accu[mf][nf], 0, 0, 0); \
        }                                                                     \
      }                                                                       \
      __builtin_amdgcn_s_setprio(0);                                          \
      LGKM0;                                                                  \
      if (hB) { VMW(8); } else { VMW(0); }                                    \
      SBAR; SCHED0;                                                           \
    }

    for (int kt = 0; kt < NK; kt += 2) {
      GU_STEP(0, kt, br1, br2);
      GU_STEP(1, kt + 1, br2, br1);
    }
#undef GU_STEP

    // epilogue: silu(g)*u -> bf16
    #pragma unroll
    for (int mf = 0; mf < 4; ++mf)
      #pragma unroll
      for (int nf = 0; nf < 2; ++nf)
        #pragma unroll
        for (int v = 0; v < 4; ++v) {
          int rr = wr * 64 + mf * 16 + r * 4 + v;
          if (m0 + rr < nrows) {
            float g = accg[mf][nf][v], u = accu[mf][nf][v];
            float s = g / (1.f + __expf(-g));
            hout[(size_t)(rowbase + m0 + rr) * N + n0 + wc * 32 + nf * 16 + c] = f2b(s * u);
          }
        }
  }
}

// =================================================================
// Down-proj grouped GEMM, routed (y<NEXP) + shared (y==NEXP) merged.
// Same pipeline; single B mat staged as per-thread 4-runs (ds_write_b64).
// Output: atomicAdd into memset-zeroed out (weighted for routed).
// =================================================================
__global__ __launch_bounds__(512, 4) void k_down4(
    const unsigned short* __restrict__ hb, const unsigned short* __restrict__ sh,
    const float* __restrict__ wd_r, const float* __restrict__ wsd,
    const int* __restrict__ offp, const int* __restrict__ cnt,
    const int* __restrict__ tok, const float* __restrict__ wts,
    float* __restrict__ out)
{
  const int ey = blockIdx.y;
  const bool se = (ey == NEXP);
  const int K = se ? SHI : I_EXP;
  const int n0 = blockIdx.x * 64;

  int rowbase, nrows;
  if (se) { rowbase = 0; nrows = T_TOK; }
  else    { rowbase = offp[ey]; nrows = cnt[ey]; }
  if (nrows <= 0) return;

  const unsigned short* hin = se ? sh : hb;
  const float* wdp = se ? wsd : wd_r + (size_t)ey * I_EXP * D_HID;

  __shared__ __align__(16) unsigned short As[2][8192];
  __shared__ __align__(16) unsigned short Bls[2][64 * 36];

  const int tid = threadIdx.x;
  const int wid = tid >> 6, lane = tid & 63;
  const int c = lane & 15, r = lane >> 4;
  const int wr = wid >> 1, wc = wid & 1;

  const int bko = wid & 3;
  const int half = wid >> 2;     // 0/1: k-sub within octet
  const float* bsrc = wdp + (size_t)(bko * 8 + half * 4) * D_HID + n0 + lane;
  const int bwoff = lane * 36 + bko * 8 + half * 4;

  int aoff[4];
  #pragma unroll
  for (int mf = 0; mf < 4; ++mf)
    aoff[mf] = (r * 256 + wr * 64 + mf * 16 + c) * 8;
  int boff[2];
  #pragma unroll
  for (int nf = 0; nf < 2; ++nf)
    boff[nf] = (wc * 32 + nf * 16 + c) * 36 + r * 8;

  const int NK = K / 32;   // 44 or 88 (even)

  for (int m0 = 0; m0 < nrows; m0 += 256) {
    const unsigned short* ga;
    {
      int rl = min(m0 + (tid & 255), nrows - 1);
      ga = hin + (size_t)(rowbase + rl) * K + (tid >> 8) * 8;
    }

    floatx4 acc[4][2] = {};
    float br1[4], br2[4];

    #pragma unroll
    for (int j = 0; j < 4; ++j) br2[j] = bsrc[(size_t)j * D_HID];
    gld_lds16(ga, &As[0][(size_t)tid * 8]);
    gld_lds16(ga + 16, &As[0][(size_t)(512 + tid) * 8]);
    #pragma unroll
    for (int j = 0; j < 4; ++j) br1[j] = bsrc[(size_t)(32 + j) * D_HID];
    { uint2 pw = pack4(br2); *(uint2*)&Bls[0][bwoff] = pw; }
    LGKM0; VMW(4); SBAR; SCHED0;

#define DN_STEP(BUF, KT, BRW, BRL)                                            \
    {                                                                         \
      const int kt_ = (KT);                                                   \
      const bool hA = (kt_ + 1 < NK), hB = (kt_ + 2 < NK);                    \
      if (hA) {                                                               \
        const unsigned short* gap = ga + (kt_ + 1) * 32;                      \
        gld_lds16(gap, &As[BUF ^ 1][(size_t)tid * 8]);                        \
        gld_lds16(gap + 16, &As[BUF ^ 1][(size_t)(512 + tid) * 8]);           \
      }                                                                       \
      if (hB) {                                                               \
        const float* bs_ = bsrc + (size_t)(kt_ + 2) * 32 * D_HID;             \
        _Pragma("unroll")                                                     \
        for (int j = 0; j < 4; ++j) BRL[j] = bs_[(size_t)j * D_HID];          \
      }                                                                       \
      if (hA) { uint2 pw = pack4(BRW); *(uint2*)&Bls[BUF ^ 1][bwoff] = pw; }  \
      short8 af[4];                                                           \
      _Pragma("unroll")                                                       \
      for (int mf = 0; mf < 4; ++mf) af[mf] = *(const short8*)&As[BUF][aoff[mf]]; \
      __builtin_amdgcn_s_setprio(1);                                          \
      _Pragma("unroll")                                                       \
      for (int nf = 0; nf < 2; ++nf) {                                        \
        short8 fd = *(const short8*)&Bls[BUF][boff[nf]];                      \
        _Pragma("unroll")                                                     \
        for (int mf = 0; mf < 4; ++mf)                                        \
          acc[mf][nf] = __builtin_amdgcn_mfma_f32_16x16x32_bf16(af[mf], fd, acc[mf][nf], 0, 0, 0); \
      }                                                                       \
      __builtin_amdgcn_s_setprio(0);                                          \
      LGKM0;                                                                  \
      if (hB) { VMW(4); } else { VMW(0); }                                    \
      SBAR; SCHED0;                                                           \
    }

    for (int kt = 0; kt < NK; kt += 2) {
      DN_STEP(0, kt, br1, br2);
      DN_STEP(1, kt + 1, br2, br1);
    }
#undef DN_STEP

    #pragma unroll
    for (int mf = 0; mf < 4; ++mf)
      #pragma unroll
      for (int nf = 0; nf < 2; ++nf)
        #pragma unroll
        for (int v = 0; v < 4; ++v) {
          int rr = wr * 64 + mf * 16 + r * 4 + v;
          if (m0 + rr < nrows) {
            int grow = rowbase + m0 + rr;
            int tk = se ? grow : tok[grow];
            float w = se ? 1.0f : wts[grow] * RSCALE;
            atomicAdd(&out[(size_t)tk * D_HID + n0 + wc * 32 + nf * 16 + c],
                      w * acc[mf][nf][v]);
          }
        }
  }
}

extern "C" void kernel_launch(void* const* d_in, const int* in_sizes, int n_in,
                              void* d_out, int out_size, void* d_ws, size_t ws_size,
                              hipStream_t stream) {
  const float* x    = (const float*)d_in[0];
  const float* gw   = (const float*)d_in[1];
  const float* bias = (const float*)d_in[2];
  const float* wg   = (const float*)d_in[3];
  const float* wu   = (const float*)d_in[4];
  const float* wd   = (const float*)d_in[5];
  const float* wsg  = (const float*)d_in[6];
  const float* wsu  = (const float*)d_in[7];
  const float* wsd  = (const float*)d_in[8];
  float* out = (float*)d_out;

  char* ws = (char*)d_ws;
  size_t o = 0;
  auto take = [&](size_t bytes) {
    char* p = ws + o;
    o += (bytes + 255) & ~(size_t)255;
    return p;
  };
  int*   tki  = (int*)  take((size_t)T_TOK * TOPK * 4);
  float* tkw  = (float*)take((size_t)T_TOK * TOPK * 4);
  int*   cnt  = (int*)  take(NEXP * 4);
  int*   offp = (int*)  take((NEXP + 1) * 4);
  int*   tok  = (int*)  take((size_t)T_TOK * TOPK * 4);
  float* wts  = (float*)take((size_t)T_TOK * TOPK * 4);
  unsigned short* xb = (unsigned short*)take((size_t)T_TOK * D_HID * 2);
  unsigned short* hb = (unsigned short*)take((size_t)T_TOK * TOPK * I_EXP * 2);
  unsigned short* sh = (unsigned short*)take((size_t)T_TOK * SHI * 2);

  hipMemsetAsync(out, 0, (size_t)T_TOK * D_HID * sizeof(float), stream);
  k_route<<<T_TOK, 64, 0, stream>>>(x, gw, bias, tki, tkw);
  k_count<<<1, 256, 0, stream>>>(tki, cnt, offp);
  k_compact<<<NEXP, 64, 0, stream>>>(tki, tkw, offp, tok, wts);
  k_cast<<<(T_TOK * D_HID / 4 + 255) / 256, 256, 0, stream>>>(x, xb, T_TOK * D_HID / 4);

  // merged gate+up: routed experts (y<32) + shared (y=32, dense, N=SHI)
  k_gateup4<<<dim3(SHI / 64, NEXP + 1), 512, 0, stream>>>(
      xb, wg, wu, wsg, wsu, offp, cnt, tok, hb, sh);
  // merged down: routed (atomic, weighted) + shared (atomic, w=1)
  k_down4<<<dim3(D_HID / 64, NEXP + 1), 512, 0, stream>>>(
      hb, sh, wd, wsd, offp, cnt, tok, wts, out);
}

// Round 7
// 1025.004 us; speedup vs baseline: 4.4978x; 4.4978x over previous
//
#include <hip/hip_runtime.h>

#define T_TOK 1024
#define D_HID 2048
#define NEXP 32
#define I_EXP 1408
#define TOPK 6
#define NGRP 8
#define GSIZE 4
#define TOPG 3
#define SHI 2816
#define RSCALE 2.5f

typedef __attribute__((ext_vector_type(8))) short short8;
typedef __attribute__((ext_vector_type(4))) float floatx4;

__device__ __forceinline__ unsigned short f2b(float f) {
  unsigned int u = __float_as_uint(f);
  u += 0x7fffu + ((u >> 16) & 1u);   // RNE
  return (unsigned short)(u >> 16);
}

__device__ __forceinline__ void gld_lds16(const void* g, void* l) {
  __builtin_amdgcn_global_load_lds(
      (const __attribute__((address_space(1))) unsigned int*)g,
      (__attribute__((address_space(3))) unsigned int*)l, 16, 0, 0);
}

__device__ __forceinline__ uint4 pack8(const float* v) {
  uint4 o;
  o.x = (unsigned)f2b(v[0]) | ((unsigned)f2b(v[1]) << 16);
  o.y = (unsigned)f2b(v[2]) | ((unsigned)f2b(v[3]) << 16);
  o.z = (unsigned)f2b(v[4]) | ((unsigned)f2b(v[5]) << 16);
  o.w = (unsigned)f2b(v[6]) | ((unsigned)f2b(v[7]) << 16);
  return o;
}

__device__ __forceinline__ uint2 pack4(const float* v) {
  uint2 o;
  o.x = (unsigned)f2b(v[0]) | ((unsigned)f2b(v[1]) << 16);
  o.y = (unsigned)f2b(v[2]) | ((unsigned)f2b(v[3]) << 16);
  return o;
}

// ---------------- routing: one block (1 wave) per token ----------------
__global__ __launch_bounds__(64) void k_route(
    const float* __restrict__ x, const float* __restrict__ gw,
    const float* __restrict__ bias, int* __restrict__ tki, float* __restrict__ tkw)
{
  int t = blockIdx.x;
  __shared__ float xs[D_HID];
  __shared__ float sc[NEXP], cor[NEXP];
  int lane = threadIdx.x;
  for (int d = lane * 4; d < D_HID; d += 64 * 4)
    *(float4*)(xs + d) = *(const float4*)(x + (size_t)t * D_HID + d);
  __syncthreads();
  if (lane < NEXP) {
    float acc = 0.f;
    for (int d = 0; d < D_HID; ++d) acc += xs[d] * gw[d * NEXP + lane];
    float s = 1.f / (1.f + expf(-acc));
    sc[lane] = s;
    cor[lane] = s + bias[lane];
  }
  __syncthreads();
  if (lane == 0) {
    float gs[NGRP];
    for (int g = 0; g < NGRP; ++g) {
      float m1 = -INFINITY, m2 = -INFINITY;
      for (int j = 0; j < GSIZE; ++j) {
        float v = cor[g * GSIZE + j];
        if (v > m1) { m2 = m1; m1 = v; } else if (v > m2) m2 = v;
      }
      gs[g] = m1 + m2;
    }
    unsigned gmask = 0;
    for (int rr = 0; rr < TOPG; ++rr) {
      int bi = -1; float bv = -INFINITY;
      for (int g = 0; g < NGRP; ++g)
        if (!((gmask >> g) & 1) && gs[g] > bv) { bv = gs[g]; bi = g; }
      gmask |= 1u << bi;
    }
    unsigned used = 0;
    float wsum = 0.f;
    int idxs[TOPK]; float wsel[TOPK];
    for (int rr = 0; rr < TOPK; ++rr) {
      int bi = -1; float bv = -INFINITY;
      for (int e = 0; e < NEXP; ++e) {
        if (!((gmask >> (e / GSIZE)) & 1)) continue;
        if ((used >> e) & 1) continue;
        if (cor[e] > bv) { bv = cor[e]; bi = e; }
      }
      used |= 1u << bi;
      idxs[rr] = bi; wsel[rr] = sc[bi]; wsum += sc[bi];
    }
    float inv = 1.f / (wsum + 1e-20f);
    for (int rr = 0; rr < TOPK; ++rr) {
      tki[t * TOPK + rr] = idxs[rr];
      tkw[t * TOPK + rr] = wsel[rr] * inv;
    }
  }
}

// ---------------- counts + offsets (single block) ----------------
__global__ __launch_bounds__(256) void k_count(const int* __restrict__ tki,
                                               int* __restrict__ cnt, int* __restrict__ offp)
{
  __shared__ int c[NEXP];
  if (threadIdx.x < NEXP) c[threadIdx.x] = 0;
  __syncthreads();
  for (int i = threadIdx.x; i < T_TOK * TOPK; i += 256) atomicAdd(&c[tki[i]], 1);
  __syncthreads();
  if (threadIdx.x == 0) {
    int s = 0;
    for (int e = 0; e < NEXP; ++e) { offp[e] = s; cnt[e] = c[e]; s += c[e]; }
    offp[NEXP] = s;
  }
}

// ---------------- deterministic compaction: one wave per expert ----------------
__global__ __launch_bounds__(64) void k_compact(
    const int* __restrict__ tki, const float* __restrict__ tkw,
    const int* __restrict__ offp, int* __restrict__ tok, float* __restrict__ wts)
{
  int e = blockIdx.x, lane = threadIdx.x;
  int base = offp[e];
  for (int t0 = 0; t0 < T_TOK; t0 += 64) {
    int t = t0 + lane;
    int found = -1;
    for (int j = 0; j < TOPK; ++j)
      if (tki[t * TOPK + j] == e) found = j;
    unsigned long long m = __ballot(found >= 0);
    if (found >= 0) {
      int pos = base + __popcll(m & ((1ull << lane) - 1ull));
      tok[pos] = t;
      wts[pos] = tkw[t * TOPK + found];
    }
    base += __popcll(m);
  }
}

// ---------------- fp32 -> bf16 cast of hidden states ----------------
__global__ __launch_bounds__(256) void k_cast(const float* __restrict__ x,
                                              unsigned short* __restrict__ xb, int n4)
{
  int i = blockIdx.x * 256 + threadIdx.x;
  if (i < n4) {
    float4 v = ((const float4*)x)[i];
    ushort4 o;
    o.x = f2b(v.x); o.y = f2b(v.y); o.z = f2b(v.z); o.w = f2b(v.w);
    ((ushort4*)xb)[i] = o;
  }
}

// =================================================================
// Templated GEMM bodies.  512 thr / 8 waves (4M x 2N), tile 256m x 64n,
// BK=32, double-buffered LDS, compiler-scheduled depth-1 (__syncthreads).
// A: gld_lds, [koff][m] 16B-granule layout (conflict-free b128 frag reads,
//    linear LDS dest).  B: per-thread k-run, [n][k] pad 36 (conflict-free
//    b128 writes and reads).  No inline-asm pins -> no forced liveness.
// =================================================================

template<int N, int K>
__device__ __forceinline__ void gemm_gu(
    const unsigned short* __restrict__ xb,
    const float* __restrict__ wgp, const float* __restrict__ wup,
    const int* __restrict__ tok, int rowbase, int nrows,
    unsigned short* __restrict__ hout, int n0,
    unsigned short* As /*2*8192*/, unsigned short* Bls /*2*2*2304*/)
{
  const int tid = threadIdx.x;
  const int wid = tid >> 6, lane = tid & 63;
  const int c = lane & 15, r = lane >> 4;
  const int wr = wid >> 1, wc = wid & 1;

  const int mat = wid >> 2;          // 0=gate, 1=up
  const int bko = wid & 3;           // k-octet
  const float* bsrc = (mat ? wup : wgp) + (size_t)(bko * 8) * N + n0 + lane;
  const int bwoff = lane * 36 + bko * 8 + mat * 2304;

  int aoff[4];
  #pragma unroll
  for (int mf = 0; mf < 4; ++mf)
    aoff[mf] = (r * 256 + wr * 64 + mf * 16 + c) * 8;
  int boff[2];
  #pragma unroll
  for (int nf = 0; nf < 2; ++nf)
    boff[nf] = (wc * 32 + nf * 16 + c) * 36 + r * 8;

  constexpr int NK = K / 32;

  for (int m0 = 0; m0 < nrows; m0 += 256) {
    const unsigned short* ga;
    {
      int rl = min(m0 + (tid & 255), nrows - 1);
      int tA = tok ? tok[rowbase + rl] : (rowbase + rl);
      ga = xb + (size_t)tA * K + (tid >> 8) * 8;
    }

    floatx4 accg[4][2] = {};
    floatx4 accu[4][2] = {};
    float br[8];

    // prologue: B(0) -> LDS buf0, A(0) -> buf0, B(1) -> regs
    #pragma unroll
    for (int j = 0; j < 8; ++j) br[j] = bsrc[(size_t)j * N];
    { uint4 pw = pack8(br); *(uint4*)&Bls[bwoff] = pw; }
    gld_lds16(ga, As + (size_t)tid * 8);
    gld_lds16(ga + 16, As + (size_t)(512 + tid) * 8);
    #pragma unroll
    for (int j = 0; j < 8; ++j) br[j] = bsrc[(size_t)(32 + j) * N];
    __syncthreads();

    int b = 0;
    for (int kt = 0; kt < NK; ++kt) {
      if (kt + 1 < NK) {
        { uint4 pw = pack8(br); *(uint4*)&Bls[(b ^ 1) * 4608 + bwoff] = pw; }
        const unsigned short* gap = ga + (kt + 1) * 32;
        gld_lds16(gap, As + (size_t)((b ^ 1) * 8192 + tid * 8));
        gld_lds16(gap + 16, As + (size_t)((b ^ 1) * 8192 + 4096 + tid * 8));
      }
      if (kt + 2 < NK) {
        const float* bs = bsrc + (size_t)(kt + 2) * 32 * N;
        #pragma unroll
        for (int j = 0; j < 8; ++j) br[j] = bs[(size_t)j * N];
      }
      short8 af[4];
      #pragma unroll
      for (int mf = 0; mf < 4; ++mf)
        af[mf] = *(const short8*)(As + b * 8192 + aoff[mf]);
      #pragma unroll
      for (int nf = 0; nf < 2; ++nf) {
        short8 fg = *(const short8*)(Bls + b * 4608 + boff[nf]);
        short8 fu = *(const short8*)(Bls + b * 4608 + 2304 + boff[nf]);
        #pragma unroll
        for (int mf = 0; mf < 4; ++mf) {
          accg[mf][nf] = __builtin_amdgcn_mfma_f32_16x16x32_bf16(af[mf], fg, accg[mf][nf], 0, 0, 0);
          accu[mf][nf] = __builtin_amdgcn_mfma_f32_16x16x32_bf16(af[mf], fu, accu[mf][nf], 0, 0, 0);
        }
      }
      __syncthreads();
      b ^= 1;
    }

    // epilogue: silu(g)*u -> bf16
    #pragma unroll
    for (int mf = 0; mf < 4; ++mf)
      #pragma unroll
      for (int nf = 0; nf < 2; ++nf)
        #pragma unroll
        for (int v = 0; v < 4; ++v) {
          int rr = wr * 64 + mf * 16 + r * 4 + v;
          if (m0 + rr < nrows) {
            float g = accg[mf][nf][v], u = accu[mf][nf][v];
            float s = g / (1.f + __expf(-g));
            hout[(size_t)(rowbase + m0 + rr) * N + n0 + wc * 32 + nf * 16 + c] = f2b(s * u);
          }
        }
  }
}

template<int N, int K>
__device__ __forceinline__ void gemm_dn(
    const unsigned short* __restrict__ hin,
    const float* __restrict__ wdp,
    const int* __restrict__ tok, const float* __restrict__ wts,
    int rowbase, int nrows,
    float* __restrict__ out, int n0,
    unsigned short* As /*2*8192*/, unsigned short* Bls /*2*2304*/)
{
  const int tid = threadIdx.x;
  const int wid = tid >> 6, lane = tid & 63;
  const int c = lane & 15, r = lane >> 4;
  const int wr = wid >> 1, wc = wid & 1;

  const int bko = wid & 3;
  const int half = wid >> 2;     // 0/1
  const float* bsrc = wdp + (size_t)(bko * 8 + half * 4) * N + n0 + lane;
  const int bwoff = lane * 36 + bko * 8 + half * 4;

  int aoff[4];
  #pragma unroll
  for (int mf = 0; mf < 4; ++mf)
    aoff[mf] = (r * 256 + wr * 64 + mf * 16 + c) * 8;
  int boff[2];
  #pragma unroll
  for (int nf = 0; nf < 2; ++nf)
    boff[nf] = (wc * 32 + nf * 16 + c) * 36 + r * 8;

  constexpr int NK = K / 32;

  for (int m0 = 0; m0 < nrows; m0 += 256) {
    const unsigned short* ga;
    {
      int rl = min(m0 + (tid & 255), nrows - 1);
      ga = hin + (size_t)(rowbase + rl) * K + (tid >> 8) * 8;
    }

    floatx4 acc[4][2] = {};
    float br[4];

    #pragma unroll
    for (int j = 0; j < 4; ++j) br[j] = bsrc[(size_t)j * N];
    { uint2 pw = pack4(br); *(uint2*)&Bls[bwoff] = pw; }
    gld_lds16(ga, As + (size_t)tid * 8);
    gld_lds16(ga + 16, As + (size_t)(512 + tid) * 8);
    #pragma unroll
    for (int j = 0; j < 4; ++j) br[j] = bsrc[(size_t)(32 + j) * N];
    __syncthreads();

    int b = 0;
    for (int kt = 0; kt < NK; ++kt) {
      if (kt + 1 < NK) {
        { uint2 pw = pack4(br); *(uint2*)&Bls[(b ^ 1) * 2304 + bwoff] = pw; }
        const unsigned short* gap = ga + (kt + 1) * 32;
        gld_lds16(gap, As + (size_t)((b ^ 1) * 8192 + tid * 8));
        gld_lds16(gap + 16, As + (size_t)((b ^ 1) * 8192 + 4096 + tid * 8));
      }
      if (kt + 2 < NK) {
        const float* bs = bsrc + (size_t)(kt + 2) * 32 * N;
        #pragma unroll
        for (int j = 0; j < 4; ++j) br[j] = bs[(size_t)j * N];
      }
      short8 af[4];
      #pragma unroll
      for (int mf = 0; mf < 4; ++mf)
        af[mf] = *(const short8*)(As + b * 8192 + aoff[mf]);
      #pragma unroll
      for (int nf = 0; nf < 2; ++nf) {
        short8 fd = *(const short8*)(Bls + b * 2304 + boff[nf]);
        #pragma unroll
        for (int mf = 0; mf < 4; ++mf)
          acc[mf][nf] = __builtin_amdgcn_mfma_f32_16x16x32_bf16(af[mf], fd, acc[mf][nf], 0, 0, 0);
      }
      __syncthreads();
      b ^= 1;
    }

    #pragma unroll
    for (int mf = 0; mf < 4; ++mf)
      #pragma unroll
      for (int nf = 0; nf < 2; ++nf)
        #pragma unroll
        for (int v = 0; v < 4; ++v) {
          int rr = wr * 64 + mf * 16 + r * 4 + v;
          if (m0 + rr < nrows) {
            int grow = rowbase + m0 + rr;
            int tk = tok ? tok[grow] : grow;
            float w = wts ? wts[grow] * RSCALE : 1.0f;
            atomicAdd(&out[(size_t)tk * N + n0 + wc * 32 + nf * 16 + c],
                      w * acc[mf][nf][v]);
          }
        }
  }
}

// grid.y: 0..31 routed experts, 32..35 shared chunks
__global__ __launch_bounds__(512, 4) void k_gu6(
    const unsigned short* __restrict__ xb,
    const float* __restrict__ wg, const float* __restrict__ wu,
    const float* __restrict__ wsg, const float* __restrict__ wsu,
    const int* __restrict__ offp, const int* __restrict__ cnt,
    const int* __restrict__ tok,
    unsigned short* __restrict__ hb, unsigned short* __restrict__ sh)
{
  __shared__ __align__(16) unsigned short As[2][8192];
  __shared__ __align__(16) unsigned short Bls[2][2][2304];
  const int ey = blockIdx.y;
  const int n0 = blockIdx.x * 64;
  if (ey < NEXP) {
    if (n0 >= I_EXP) return;
    int rowbase = offp[ey], nrows = cnt[ey];
    if (nrows <= 0) return;
    gemm_gu<I_EXP, D_HID>(xb, wg + (size_t)ey * D_HID * I_EXP,
                          wu + (size_t)ey * D_HID * I_EXP,
                          tok, rowbase, nrows, hb, n0,
                          &As[0][0], &Bls[0][0][0]);
  } else {
    gemm_gu<SHI, D_HID>(xb, wsg, wsu, nullptr, (ey - NEXP) * 256, 256,
                        sh, n0, &As[0][0], &Bls[0][0][0]);
  }
}

__global__ __launch_bounds__(512, 4) void k_dn6(
    const unsigned short* __restrict__ hb, const unsigned short* __restrict__ sh,
    const float* __restrict__ wd, const float* __restrict__ wsd,
    const int* __restrict__ offp, const int* __restrict__ cnt,
    const int* __restrict__ tok, const float* __restrict__ wts,
    float* __restrict__ out)
{
  __shared__ __align__(16) unsigned short As[2][8192];
  __shared__ __align__(16) unsigned short Bls[2][2304];
  const int ey = blockIdx.y;
  const int n0 = blockIdx.x * 64;
  if (ey < NEXP) {
    int rowbase = offp[ey], nrows = cnt[ey];
    if (nrows <= 0) return;
    gemm_dn<D_HID, I_EXP>(hb, wd + (size_t)ey * I_EXP * D_HID,
                          tok, wts, rowbase, nrows, out, n0,
                          &As[0][0], &Bls[0][0]);
  } else {
    gemm_dn<D_HID, SHI>(sh, wsd, nullptr, nullptr, (ey - NEXP) * 256, 256,
                        out, n0, &As[0][0], &Bls[0][0]);
  }
}

extern "C" void kernel_launch(void* const* d_in, const int* in_sizes, int n_in,
                              void* d_out, int out_size, void* d_ws, size_t ws_size,
                              hipStream_t stream) {
  const float* x    = (const float*)d_in[0];
  const float* gw   = (const float*)d_in[1];
  const float* bias = (const float*)d_in[2];
  const float* wg   = (const float*)d_in[3];
  const float* wu   = (const float*)d_in[4];
  const float* wd   = (const float*)d_in[5];
  const float* wsg  = (const float*)d_in[6];
  const float* wsu  = (const float*)d_in[7];
  const float* wsd  = (const float*)d_in[8];
  float* out = (float*)d_out;

  char* ws = (char*)d_ws;
  size_t o = 0;
  auto take = [&](size_t bytes) {
    char* p = ws + o;
    o += (bytes + 255) & ~(size_t)255;
    return p;
  };
  int*   tki  = (int*)  take((size_t)T_TOK * TOPK * 4);
  float* tkw  = (float*)take((size_t)T_TOK * TOPK * 4);
  int*   cnt  = (int*)  take(NEXP * 4);
  int*   offp = (int*)  take((NEXP + 1) * 4);
  int*   tok  = (int*)  take((size_t)T_TOK * TOPK * 4);
  float* wts  = (float*)take((size_t)T_TOK * TOPK * 4);
  unsigned short* xb = (unsigned short*)take((size_t)T_TOK * D_HID * 2);
  unsigned short* hb = (unsigned short*)take((size_t)T_TOK * TOPK * I_EXP * 2);
  unsigned short* sh = (unsigned short*)take((size_t)T_TOK * SHI * 2);

  (void)hipMemsetAsync(out, 0, (size_t)T_TOK * D_HID * sizeof(float), stream);
  k_route<<<T_TOK, 64, 0, stream>>>(x, gw, bias, tki, tkw);
  k_count<<<1, 256, 0, stream>>>(tki, cnt, offp);
  k_compact<<<NEXP, 64, 0, stream>>>(tki, tkw, offp, tok, wts);
  k_cast<<<(T_TOK * D_HID / 4 + 255) / 256, 256, 0, stream>>>(x, xb, T_TOK * D_HID / 4);

  // merged gate+up: routed experts (y<32) + shared chunks (y=32..35)
  k_gu6<<<dim3(SHI / 64, NEXP + 4), 512, 0, stream>>>(
      xb, wg, wu, wsg, wsu, offp, cnt, tok, hb, sh);
  // merged down: routed (weighted atomic) + shared (atomic, w=1)
  k_dn6<<<dim3(D_HID / 64, NEXP + 4), 512, 0, stream>>>(
      hb, sh, wd, wsd, offp, cnt, tok, wts, out);
}